// Round 1
// baseline (252.768 us; speedup 1.0000x reference)
//
#include <hip/hip_runtime.h>
#include <hip/hip_bf16.h>

// Problem constants (from reference): E=32768, K=32, D=128, H=4, dh=32, C=10
constexpr int E_EDGES = 32768;
constexpr int DIM = 128;

// ---------------------------------------------------------------------------
// Kernel 0: Wf = Wo @ W1   (128x128 @ 128x128) — fuses the Wo GEMM into W1
// since there is no bias/nonlinearity between them.
__global__ __launch_bounds__(256) void k_wfuse(const float* __restrict__ Wo,
                                               const float* __restrict__ W1,
                                               float* __restrict__ Wf) {
    int idx = blockIdx.x * 256 + threadIdx.x;   // 0..16383
    int r = idx >> 7, c = idx & 127;
    float acc = 0.f;
#pragma unroll 16
    for (int k = 0; k < 128; ++k) acc = fmaf(Wo[r * 128 + k], W1[k * 128 + c], acc);
    Wf[idx] = acc;
}

// ---------------------------------------------------------------------------
// Kernel 1: fused QKV projection. C = A @ W, A=[E,128], W=[128,128].
// BM=BN=64, full K=128 staged in LDS. 256 threads, 4x4 micro-tile each.
// grid = (E/64, 2, 3); z selects {Wq->q, Wk->k, Wv->v}.
__global__ __launch_bounds__(256) void k_qkv(
    const float* __restrict__ feats,
    const float* __restrict__ Wq, const float* __restrict__ Wk,
    const float* __restrict__ Wv,
    float* __restrict__ qo, float* __restrict__ ko, float* __restrict__ vo) {
    const float* W;
    float* dst;
    if (blockIdx.z == 0)      { W = Wq; dst = qo; }
    else if (blockIdx.z == 1) { W = Wk; dst = ko; }
    else                      { W = Wv; dst = vo; }

    __shared__ float As[64 * 132];   // pad 128->132 to break bank conflicts
    __shared__ float Bs[128 * 68];   // pad 64->68

    const int t = threadIdx.x;
    const int row0 = blockIdx.x * 64;
    const int col0 = blockIdx.y * 64;

    // Stage A tile (64x128): 2048 float4, coalesced.
    {
        const float4* src = (const float4*)(feats + (size_t)row0 * DIM);
#pragma unroll
        for (int p = 0; p < 8; ++p) {
            int id = t + p * 256;
            int r = id >> 5, c4 = id & 31;
            float4 v = src[r * 32 + c4];
            *(float4*)&As[r * 132 + c4 * 4] = v;
        }
    }
    // Stage B tile (128x64): 2048 float4, coalesced.
    {
#pragma unroll
        for (int p = 0; p < 8; ++p) {
            int id = t + p * 256;
            int kk = id >> 4, c4 = id & 15;
            float4 v = *(const float4*)(W + kk * DIM + col0 + c4 * 4);
            *(float4*)&Bs[kk * 68 + c4 * 4] = v;
        }
    }
    __syncthreads();

    const int tx = t & 15, ty = t >> 4;
    float acc[4][4] = {};
#pragma unroll 8
    for (int kk = 0; kk < 128; ++kk) {
        float a0 = As[(ty * 4 + 0) * 132 + kk];
        float a1 = As[(ty * 4 + 1) * 132 + kk];
        float a2 = As[(ty * 4 + 2) * 132 + kk];
        float a3 = As[(ty * 4 + 3) * 132 + kk];
        float4 b = *(float4*)&Bs[kk * 68 + tx * 4];
        acc[0][0] = fmaf(a0, b.x, acc[0][0]); acc[0][1] = fmaf(a0, b.y, acc[0][1]);
        acc[0][2] = fmaf(a0, b.z, acc[0][2]); acc[0][3] = fmaf(a0, b.w, acc[0][3]);
        acc[1][0] = fmaf(a1, b.x, acc[1][0]); acc[1][1] = fmaf(a1, b.y, acc[1][1]);
        acc[1][2] = fmaf(a1, b.z, acc[1][2]); acc[1][3] = fmaf(a1, b.w, acc[1][3]);
        acc[2][0] = fmaf(a2, b.x, acc[2][0]); acc[2][1] = fmaf(a2, b.y, acc[2][1]);
        acc[2][2] = fmaf(a2, b.z, acc[2][2]); acc[2][3] = fmaf(a2, b.w, acc[2][3]);
        acc[3][0] = fmaf(a3, b.x, acc[3][0]); acc[3][1] = fmaf(a3, b.y, acc[3][1]);
        acc[3][2] = fmaf(a3, b.z, acc[3][2]); acc[3][3] = fmaf(a3, b.w, acc[3][3]);
    }
#pragma unroll
    for (int i = 0; i < 4; ++i) {
        float4 o = make_float4(acc[i][0], acc[i][1], acc[i][2], acc[i][3]);
        *(float4*)(dst + (size_t)(row0 + ty * 4 + i) * DIM + col0 + tx * 4) = o;
    }
}

// ---------------------------------------------------------------------------
// Kernel 2: edge attention. One 64-lane wave per edge; 4 edges per block.
// Lane layout phase 1: g = lane>>5 (0/1), n = lane&31 (neighbor).
//   Lane computes scores (h=g, n) and (h=g+2, n) as full 32-long dots,
//   reading k rows directly (L2-resident). Softmax = shfl_xor over 32-lane
//   groups. Phase 2: lane owns float4 column d4=lane&31, halves split the
//   32 neighbors, coalesced 512B v loads, one xor-32 combine.
// ctx is written into the q buffer (q consumed into registers first).
__global__ __launch_bounds__(256) void k_attn(
    const float* qc,                       // q in, ctx out (same buffer)
    const float* __restrict__ kb, const float* __restrict__ vb,
    const int* __restrict__ adj) {
    __shared__ float attn_s[4][128];
    __shared__ int adj_s[4][32];

    const int lane = threadIdx.x & 63;
    const int wid = threadIdx.x >> 6;
    const int e = blockIdx.x * 4 + wid;
    const int n = lane & 31;
    const int g = lane >> 5;

    if (lane < 32) adj_s[wid][lane] = adj[e * 32 + lane];

    // q segments for heads g and g+2 (32 floats each) into registers.
    const float4* q4 = (const float4*)(qc + (size_t)e * DIM);
    float4 qa[8], qb[8];
#pragma unroll
    for (int j = 0; j < 8; ++j) qa[j] = q4[g * 8 + j];
#pragma unroll
    for (int j = 0; j < 8; ++j) qb[j] = q4[(g + 2) * 8 + j];

    const int row = adj_s[wid][n];
    const float4* kr0 = (const float4*)(kb + (size_t)row * DIM + g * 32);
    const float4* kr1 = (const float4*)(kb + (size_t)row * DIM + (g + 2) * 32);
    float s0 = 0.f, s1 = 0.f;
#pragma unroll
    for (int j = 0; j < 8; ++j) {
        float4 kv = kr0[j];
        s0 = fmaf(qa[j].x, kv.x, s0); s0 = fmaf(qa[j].y, kv.y, s0);
        s0 = fmaf(qa[j].z, kv.z, s0); s0 = fmaf(qa[j].w, kv.w, s0);
    }
#pragma unroll
    for (int j = 0; j < 8; ++j) {
        float4 kv = kr1[j];
        s1 = fmaf(qb[j].x, kv.x, s1); s1 = fmaf(qb[j].y, kv.y, s1);
        s1 = fmaf(qb[j].z, kv.z, s1); s1 = fmaf(qb[j].w, kv.w, s1);
    }
    const float scale = 0.17677669529663689f;   // 1/sqrt(32)
    s0 *= scale; s1 *= scale;

    // Softmax over n (32-lane groups).
    float m0 = s0, m1 = s1;
#pragma unroll
    for (int off = 16; off; off >>= 1) {
        m0 = fmaxf(m0, __shfl_xor(m0, off));
        m1 = fmaxf(m1, __shfl_xor(m1, off));
    }
    float e0 = __expf(s0 - m0), e1 = __expf(s1 - m1);
    float sum0 = e0, sum1 = e1;
#pragma unroll
    for (int off = 16; off; off >>= 1) {
        sum0 += __shfl_xor(sum0, off);
        sum1 += __shfl_xor(sum1, off);
    }
    attn_s[wid][g * 32 + n] = e0 / sum0;
    attn_s[wid][(g + 2) * 32 + n] = e1 / sum1;

    // Phase 2: ctx = attn @ vn. Lane owns float4 column d4; halves split n.
    const int d4 = lane & 31;
    const int h = d4 >> 3;
    const int nbase = (lane >> 5) * 16;
    float4 c = make_float4(0.f, 0.f, 0.f, 0.f);
#pragma unroll 4
    for (int i = 0; i < 16; ++i) {
        int nn = nbase + i;
        int r2 = adj_s[wid][nn];
        float a = attn_s[wid][h * 32 + nn];
        float4 vv = *(const float4*)(vb + (size_t)r2 * DIM + d4 * 4);
        c.x = fmaf(a, vv.x, c.x); c.y = fmaf(a, vv.y, c.y);
        c.z = fmaf(a, vv.z, c.z); c.w = fmaf(a, vv.w, c.w);
    }
    c.x += __shfl_xor(c.x, 32); c.y += __shfl_xor(c.y, 32);
    c.z += __shfl_xor(c.z, 32); c.w += __shfl_xor(c.w, 32);
    if (lane < 32) *(float4*)((float*)qc + (size_t)e * DIM + d4 * 4) = c;
}

// ---------------------------------------------------------------------------
// Kernel 3: h = gelu_tanh(ctx @ Wf + b1); logits = h @ W2 + b2.
// 64 rows per block; ctx and h staged in LDS.
__global__ __launch_bounds__(256) void k_mlp(
    const float* __restrict__ ctx, const float* __restrict__ Wf,
    const float* __restrict__ b1, const float* __restrict__ W2,
    const float* __restrict__ b2, float* __restrict__ out) {
    __shared__ float cs[64 * 132];
    __shared__ float hs[64 * 132];
    __shared__ float w2s[1280];
    __shared__ float b2s[16];
    __shared__ float b1s[128];

    const int t = threadIdx.x;
    const int row0 = blockIdx.x * 64;

    {
        const float4* src = (const float4*)(ctx + (size_t)row0 * DIM);
#pragma unroll
        for (int p = 0; p < 8; ++p) {
            int id = t + p * 256;
            int r = id >> 5, c4 = id & 31;
            *(float4*)&cs[r * 132 + c4 * 4] = src[r * 32 + c4];
        }
    }
    for (int i = t; i < 1280; i += 256) w2s[i] = W2[i];
    if (t < 10) b2s[t] = b2[t];
    if (t < 128) b1s[t] = b1[t];
    __syncthreads();

    const int tx = t & 15, ty = t >> 4;   // thread tile: 4 rows x 8 cols
    float acc[4][8] = {};
#pragma unroll 4
    for (int kk = 0; kk < 128; ++kk) {
        float a0 = cs[(ty * 4 + 0) * 132 + kk];
        float a1 = cs[(ty * 4 + 1) * 132 + kk];
        float a2 = cs[(ty * 4 + 2) * 132 + kk];
        float a3 = cs[(ty * 4 + 3) * 132 + kk];
        float4 w0 = *(const float4*)(Wf + kk * DIM + tx * 8);
        float4 w1 = *(const float4*)(Wf + kk * DIM + tx * 8 + 4);
        float wj[8] = {w0.x, w0.y, w0.z, w0.w, w1.x, w1.y, w1.z, w1.w};
#pragma unroll
        for (int j = 0; j < 8; ++j) {
            acc[0][j] = fmaf(a0, wj[j], acc[0][j]);
            acc[1][j] = fmaf(a1, wj[j], acc[1][j]);
            acc[2][j] = fmaf(a2, wj[j], acc[2][j]);
            acc[3][j] = fmaf(a3, wj[j], acc[3][j]);
        }
    }
#pragma unroll
    for (int i = 0; i < 4; ++i) {
#pragma unroll
        for (int j = 0; j < 8; ++j) {
            int c = tx * 8 + j;
            float x = acc[i][j] + b1s[c];
            // tanh-approx GELU (matches jax.nn.gelu approximate=True)
            float u = 0.7978845608028654f * (x + 0.044715f * x * x * x);
            float ex = __expf(2.f * u);
            float th = 1.f - 2.f / (ex + 1.f);
            hs[(ty * 4 + i) * 132 + c] = 0.5f * x * (1.f + th);
        }
    }
    __syncthreads();

    // logits: 64 rows x 10 classes = 640 outputs.
    for (int idx = t; idx < 640; idx += 256) {
        int r = idx / 10, c = idx - r * 10;
        float acc2 = b2s[c];
#pragma unroll 16
        for (int kk = 0; kk < 128; ++kk)
            acc2 = fmaf(hs[r * 132 + kk], w2s[kk * 10 + c], acc2);
        out[(size_t)(row0 + r) * 10 + c] = acc2;
    }
}

// ---------------------------------------------------------------------------
extern "C" void kernel_launch(void* const* d_in, const int* in_sizes, int n_in,
                              void* d_out, int out_size, void* d_ws, size_t ws_size,
                              hipStream_t stream) {
    const float* feats = (const float*)d_in[0];
    const float* Wq    = (const float*)d_in[1];
    const float* Wk    = (const float*)d_in[2];
    const float* Wv    = (const float*)d_in[3];
    const float* Wo    = (const float*)d_in[4];
    const float* W1    = (const float*)d_in[5];
    const float* b1    = (const float*)d_in[6];
    const float* W2    = (const float*)d_in[7];
    const float* b2    = (const float*)d_in[8];
    const int*   adj   = (const int*)d_in[9];
    float* out = (float*)d_out;

    float* ws = (float*)d_ws;
    const size_t ED = (size_t)E_EDGES * DIM;   // 4,194,304 floats
    float* qbuf = ws;            // q, later overwritten by ctx
    float* kbuf = ws + ED;
    float* vbuf = ws + 2 * ED;
    float* wf   = ws + 3 * ED;   // 16384 floats; total ws use ~48.1 MiB

    k_wfuse<<<64, 256, 0, stream>>>(Wo, W1, wf);
    k_qkv<<<dim3(E_EDGES / 64, 2, 3), 256, 0, stream>>>(feats, Wq, Wk, Wv,
                                                        qbuf, kbuf, vbuf);
    k_attn<<<E_EDGES / 4, 256, 0, stream>>>(qbuf, kbuf, vbuf, adj);
    k_mlp<<<E_EDGES / 64, 256, 0, stream>>>(qbuf, wf, b1, W2, b2, out);
}

// Round 2
// 152.262 us; speedup vs baseline: 1.6601x; 1.6601x over previous
//
#include <hip/hip_runtime.h>
#include <hip/hip_bf16.h>

// Problem constants (from reference): E=32768, K=32, D=128, H=4, dh=32, C=10
constexpr int E_EDGES = 32768;
constexpr int DIM = 128;

// bf16 (stored as upper 16 bits of f32) unpack helpers
__device__ inline float bflo(unsigned u) { return __uint_as_float(u << 16); }
__device__ inline float bfhi(unsigned u) { return __uint_as_float(u & 0xffff0000u); }
__device__ inline unsigned pk_bf2(float a, float b) {
    __hip_bfloat162 h = __float22bfloat162_rn(make_float2(a, b));
    return *(unsigned*)&h;
}

// ---------------------------------------------------------------------------
// Kernel 0: Wf = Wo @ W1   (128x128 @ 128x128) — fuses the Wo GEMM into W1
// since there is no bias/nonlinearity between them.
__global__ __launch_bounds__(256) void k_wfuse(const float* __restrict__ Wo,
                                               const float* __restrict__ W1,
                                               float* __restrict__ Wf) {
    int idx = blockIdx.x * 256 + threadIdx.x;   // 0..16383
    int r = idx >> 7, c = idx & 127;
    float acc = 0.f;
#pragma unroll 16
    for (int k = 0; k < 128; ++k) acc = fmaf(Wo[r * 128 + k], W1[k * 128 + c], acc);
    Wf[idx] = acc;
}

// ---------------------------------------------------------------------------
// Kernel 1: fused QKV projection. C = A @ W, A=[E,128], W=[128,128].
// BM=BN=64, full K=128 staged in LDS. 256 threads, 4x4 micro-tiles.
// grid = (E/64, 2, 3); z=0 -> q (f32), z=1 -> k (bf16), z=2 -> v (bf16).
__global__ __launch_bounds__(256) void k_qkv(
    const float* __restrict__ feats,
    const float* __restrict__ Wq, const float* __restrict__ Wk,
    const float* __restrict__ Wv,
    float* __restrict__ qo, __hip_bfloat16* __restrict__ ko,
    __hip_bfloat16* __restrict__ vo) {
    const float* W;
    if (blockIdx.z == 0)      W = Wq;
    else if (blockIdx.z == 1) W = Wk;
    else                      W = Wv;

    __shared__ float As[64 * 132];   // pad 128->132 to break bank conflicts
    __shared__ float Bs[128 * 68];   // pad 64->68

    const int t = threadIdx.x;
    const int row0 = blockIdx.x * 64;
    const int col0 = blockIdx.y * 64;

    // Stage A tile (64x128): coalesced float4.
    {
        const float4* src = (const float4*)(feats + (size_t)row0 * DIM);
#pragma unroll
        for (int p = 0; p < 8; ++p) {
            int id = t + p * 256;
            int r = id >> 5, c4 = id & 31;
            *(float4*)&As[r * 132 + c4 * 4] = src[r * 32 + c4];
        }
    }
    // Stage B tile (128x64): coalesced float4.
    {
#pragma unroll
        for (int p = 0; p < 8; ++p) {
            int id = t + p * 256;
            int kk = id >> 4, c4 = id & 15;
            *(float4*)&Bs[kk * 68 + c4 * 4] =
                *(const float4*)(W + kk * DIM + col0 + c4 * 4);
        }
    }
    __syncthreads();

    const int tx = t & 15, ty = t >> 4;
    float acc[4][4] = {};
#pragma unroll 8
    for (int kk = 0; kk < 128; ++kk) {
        float a0 = As[(ty * 4 + 0) * 132 + kk];
        float a1 = As[(ty * 4 + 1) * 132 + kk];
        float a2 = As[(ty * 4 + 2) * 132 + kk];
        float a3 = As[(ty * 4 + 3) * 132 + kk];
        float4 b = *(float4*)&Bs[kk * 68 + tx * 4];
        acc[0][0] = fmaf(a0, b.x, acc[0][0]); acc[0][1] = fmaf(a0, b.y, acc[0][1]);
        acc[0][2] = fmaf(a0, b.z, acc[0][2]); acc[0][3] = fmaf(a0, b.w, acc[0][3]);
        acc[1][0] = fmaf(a1, b.x, acc[1][0]); acc[1][1] = fmaf(a1, b.y, acc[1][1]);
        acc[1][2] = fmaf(a1, b.z, acc[1][2]); acc[1][3] = fmaf(a1, b.w, acc[1][3]);
        acc[2][0] = fmaf(a2, b.x, acc[2][0]); acc[2][1] = fmaf(a2, b.y, acc[2][1]);
        acc[2][2] = fmaf(a2, b.z, acc[2][2]); acc[2][3] = fmaf(a2, b.w, acc[2][3]);
        acc[3][0] = fmaf(a3, b.x, acc[3][0]); acc[3][1] = fmaf(a3, b.y, acc[3][1]);
        acc[3][2] = fmaf(a3, b.z, acc[3][2]); acc[3][3] = fmaf(a3, b.w, acc[3][3]);
    }
    if (blockIdx.z == 0) {
#pragma unroll
        for (int i = 0; i < 4; ++i) {
            float4 o = make_float4(acc[i][0], acc[i][1], acc[i][2], acc[i][3]);
            *(float4*)(qo + (size_t)(row0 + ty * 4 + i) * DIM + col0 + tx * 4) = o;
        }
    } else {
        __hip_bfloat16* dst = (blockIdx.z == 1) ? ko : vo;
#pragma unroll
        for (int i = 0; i < 4; ++i) {
            uint2 o;
            o.x = pk_bf2(acc[i][0], acc[i][1]);
            o.y = pk_bf2(acc[i][2], acc[i][3]);
            *(uint2*)(dst + (size_t)(row0 + ty * 4 + i) * DIM + col0 + tx * 4) = o;
        }
    }
}

// ---------------------------------------------------------------------------
// Kernel 2: edge attention over bf16 k/v. One 64-lane wave per edge;
// 4 edges per block. Phase 1: lane (g=lane>>5, n=lane&31) computes scores
// for heads g and g+2 of neighbor n — bf16 k row slices (64B each) unpacked
// with bit-ops, f32 accumulate. Softmax via 32-lane shfl_xor. Phase 2:
// lane owns 4-col group d4, halves split the 32 neighbors: per neighbor a
// fully-coalesced 256B bf16 row read; one xor-32 combine.
// ctx (f32) overwrites the q buffer (q consumed into registers first).
__global__ __launch_bounds__(256) void k_attn(
    float* qc,                                  // q in, ctx out (same buffer)
    const __hip_bfloat16* __restrict__ kb,
    const __hip_bfloat16* __restrict__ vb,
    const int* __restrict__ adj) {
    __shared__ float attn_s[4][128];
    __shared__ int adj_s[4][32];

    const int lane = threadIdx.x & 63;
    const int wid = threadIdx.x >> 6;
    const int e = blockIdx.x * 4 + wid;
    const int n = lane & 31;
    const int g = lane >> 5;

    if (lane < 32) adj_s[wid][lane] = adj[e * 32 + lane];

    // q slices for heads g and g+2 (32 floats each) into registers.
    const float4* q4 = (const float4*)(qc + (size_t)e * DIM);
    float qa[32], qb[32];
#pragma unroll
    for (int j = 0; j < 8; ++j) {
        float4 tA = q4[g * 8 + j];
        qa[j * 4 + 0] = tA.x; qa[j * 4 + 1] = tA.y;
        qa[j * 4 + 2] = tA.z; qa[j * 4 + 3] = tA.w;
        float4 tB = q4[(g + 2) * 8 + j];
        qb[j * 4 + 0] = tB.x; qb[j * 4 + 1] = tB.y;
        qb[j * 4 + 2] = tB.z; qb[j * 4 + 3] = tB.w;
    }

    const int row = adj_s[wid][n];
    const uint4* kr0 = (const uint4*)(kb + (size_t)row * DIM + g * 32);        // 4x16B
    const uint4* kr1 = (const uint4*)(kb + (size_t)row * DIM + (g + 2) * 32);  // 4x16B
    float s0 = 0.f, s1 = 0.f;
#pragma unroll
    for (int j = 0; j < 4; ++j) {
        uint4 u = kr0[j];
        s0 = fmaf(qa[j * 8 + 0], bflo(u.x), s0); s0 = fmaf(qa[j * 8 + 1], bfhi(u.x), s0);
        s0 = fmaf(qa[j * 8 + 2], bflo(u.y), s0); s0 = fmaf(qa[j * 8 + 3], bfhi(u.y), s0);
        s0 = fmaf(qa[j * 8 + 4], bflo(u.z), s0); s0 = fmaf(qa[j * 8 + 5], bfhi(u.z), s0);
        s0 = fmaf(qa[j * 8 + 6], bflo(u.w), s0); s0 = fmaf(qa[j * 8 + 7], bfhi(u.w), s0);
    }
#pragma unroll
    for (int j = 0; j < 4; ++j) {
        uint4 u = kr1[j];
        s1 = fmaf(qb[j * 8 + 0], bflo(u.x), s1); s1 = fmaf(qb[j * 8 + 1], bfhi(u.x), s1);
        s1 = fmaf(qb[j * 8 + 2], bflo(u.y), s1); s1 = fmaf(qb[j * 8 + 3], bfhi(u.y), s1);
        s1 = fmaf(qb[j * 8 + 4], bflo(u.z), s1); s1 = fmaf(qb[j * 8 + 5], bfhi(u.z), s1);
        s1 = fmaf(qb[j * 8 + 6], bflo(u.w), s1); s1 = fmaf(qb[j * 8 + 7], bfhi(u.w), s1);
    }
    const float scale = 0.17677669529663689f;   // 1/sqrt(32)
    s0 *= scale; s1 *= scale;

    // Softmax over n (32-lane groups).
    float m0 = s0, m1 = s1;
#pragma unroll
    for (int off = 16; off; off >>= 1) {
        m0 = fmaxf(m0, __shfl_xor(m0, off));
        m1 = fmaxf(m1, __shfl_xor(m1, off));
    }
    float e0 = __expf(s0 - m0), e1 = __expf(s1 - m1);
    float sum0 = e0, sum1 = e1;
#pragma unroll
    for (int off = 16; off; off >>= 1) {
        sum0 += __shfl_xor(sum0, off);
        sum1 += __shfl_xor(sum1, off);
    }
    attn_s[wid][g * 32 + n] = e0 / sum0;
    attn_s[wid][(g + 2) * 32 + n] = e1 / sum1;

    // Phase 2: ctx = attn @ vn. Lane owns 4-col group d4; halves split n.
    const int d4 = lane & 31;
    const int h = d4 >> 3;
    const int nbase = (lane >> 5) * 16;
    float4 c = make_float4(0.f, 0.f, 0.f, 0.f);
#pragma unroll 4
    for (int i = 0; i < 16; ++i) {
        int nn = nbase + i;
        int r2 = adj_s[wid][nn];
        float a = attn_s[wid][h * 32 + nn];
        uint2 u = *(const uint2*)(vb + (size_t)r2 * DIM + d4 * 4);
        c.x = fmaf(a, bflo(u.x), c.x); c.y = fmaf(a, bfhi(u.x), c.y);
        c.z = fmaf(a, bflo(u.y), c.z); c.w = fmaf(a, bfhi(u.y), c.w);
    }
    c.x += __shfl_xor(c.x, 32); c.y += __shfl_xor(c.y, 32);
    c.z += __shfl_xor(c.z, 32); c.w += __shfl_xor(c.w, 32);
    if (lane < 32) *(float4*)(qc + (size_t)e * DIM + d4 * 4) = c;
}

// ---------------------------------------------------------------------------
// Kernel 3: h = gelu_tanh(ctx @ Wf + b1); logits = h @ W2 + b2.
// 64 rows per block; ctx and h staged in LDS.
__global__ __launch_bounds__(256) void k_mlp(
    const float* __restrict__ ctx, const float* __restrict__ Wf,
    const float* __restrict__ b1, const float* __restrict__ W2,
    const float* __restrict__ b2, float* __restrict__ out) {
    __shared__ float cs[64 * 132];
    __shared__ float hs[64 * 132];
    __shared__ float w2s[1280];
    __shared__ float b2s[16];
    __shared__ float b1s[128];

    const int t = threadIdx.x;
    const int row0 = blockIdx.x * 64;

    {
        const float4* src = (const float4*)(ctx + (size_t)row0 * DIM);
#pragma unroll
        for (int p = 0; p < 8; ++p) {
            int id = t + p * 256;
            int r = id >> 5, c4 = id & 31;
            *(float4*)&cs[r * 132 + c4 * 4] = src[r * 32 + c4];
        }
    }
    for (int i = t; i < 1280; i += 256) w2s[i] = W2[i];
    if (t < 10) b2s[t] = b2[t];
    if (t < 128) b1s[t] = b1[t];
    __syncthreads();

    const int tx = t & 15, ty = t >> 4;   // thread tile: 4 rows x 8 cols
    float acc[4][8] = {};
#pragma unroll 4
    for (int kk = 0; kk < 128; ++kk) {
        float a0 = cs[(ty * 4 + 0) * 132 + kk];
        float a1 = cs[(ty * 4 + 1) * 132 + kk];
        float a2 = cs[(ty * 4 + 2) * 132 + kk];
        float a3 = cs[(ty * 4 + 3) * 132 + kk];
        float4 w0 = *(const float4*)(Wf + kk * DIM + tx * 8);
        float4 w1 = *(const float4*)(Wf + kk * DIM + tx * 8 + 4);
        float wj[8] = {w0.x, w0.y, w0.z, w0.w, w1.x, w1.y, w1.z, w1.w};
#pragma unroll
        for (int j = 0; j < 8; ++j) {
            acc[0][j] = fmaf(a0, wj[j], acc[0][j]);
            acc[1][j] = fmaf(a1, wj[j], acc[1][j]);
            acc[2][j] = fmaf(a2, wj[j], acc[2][j]);
            acc[3][j] = fmaf(a3, wj[j], acc[3][j]);
        }
    }
#pragma unroll
    for (int i = 0; i < 4; ++i) {
#pragma unroll
        for (int j = 0; j < 8; ++j) {
            int c = tx * 8 + j;
            float x = acc[i][j] + b1s[c];
            // tanh-approx GELU (matches jax.nn.gelu approximate=True)
            float u = 0.7978845608028654f * (x + 0.044715f * x * x * x);
            float ex = __expf(2.f * u);
            float th = 1.f - 2.f / (ex + 1.f);
            hs[(ty * 4 + i) * 132 + c] = 0.5f * x * (1.f + th);
        }
    }
    __syncthreads();

    // logits: 64 rows x 10 classes = 640 outputs.
    for (int idx = t; idx < 640; idx += 256) {
        int r = idx / 10, c = idx - r * 10;
        float acc2 = b2s[c];
#pragma unroll 16
        for (int kk = 0; kk < 128; ++kk)
            acc2 = fmaf(hs[r * 132 + kk], w2s[kk * 10 + c], acc2);
        out[(size_t)(row0 + r) * 10 + c] = acc2;
    }
}

// ---------------------------------------------------------------------------
extern "C" void kernel_launch(void* const* d_in, const int* in_sizes, int n_in,
                              void* d_out, int out_size, void* d_ws, size_t ws_size,
                              hipStream_t stream) {
    const float* feats = (const float*)d_in[0];
    const float* Wq    = (const float*)d_in[1];
    const float* Wk    = (const float*)d_in[2];
    const float* Wv    = (const float*)d_in[3];
    const float* Wo    = (const float*)d_in[4];
    const float* W1    = (const float*)d_in[5];
    const float* b1    = (const float*)d_in[6];
    const float* W2    = (const float*)d_in[7];
    const float* b2    = (const float*)d_in[8];
    const int*   adj   = (const int*)d_in[9];
    float* out = (float*)d_out;

    float* ws = (float*)d_ws;
    const size_t ED = (size_t)E_EDGES * DIM;   // 4,194,304 elements
    float* qbuf = ws;                                   // f32 q, later ctx
    __hip_bfloat16* kbuf = (__hip_bfloat16*)(ws + ED);  // bf16 k
    __hip_bfloat16* vbuf = kbuf + ED;                   // bf16 v
    float* wf = (float*)(vbuf + ED);                    // 16384 f32
    // total ws use: 16.7 MB + 8.4 + 8.4 + 64 KB ≈ 33.6 MB

    k_wfuse<<<64, 256, 0, stream>>>(Wo, W1, wf);
    k_qkv<<<dim3(E_EDGES / 64, 2, 3), 256, 0, stream>>>(feats, Wq, Wk, Wv,
                                                        qbuf, kbuf, vbuf);
    k_attn<<<E_EDGES / 4, 256, 0, stream>>>(qbuf, kbuf, vbuf, adj);
    k_mlp<<<E_EDGES / 64, 256, 0, stream>>>(qbuf, wf, b1, W2, b2, out);
}

// Round 3
// 150.831 us; speedup vs baseline: 1.6758x; 1.0095x over previous
//
#include <hip/hip_runtime.h>
#include <hip/hip_bf16.h>

// Problem constants (from reference): E=32768, K=32, D=128, H=4, dh=32, C=10
constexpr int E_EDGES = 32768;
constexpr int DIM = 128;

// bf16 (upper 16 bits of f32) unpack helpers
__device__ inline float bflo(unsigned u) { return __uint_as_float(u << 16); }
__device__ inline float bfhi(unsigned u) { return __uint_as_float(u & 0xffff0000u); }
__device__ inline unsigned pk_bf2(float a, float b) {
    __hip_bfloat162 h = __float22bfloat162_rn(make_float2(a, b));
    return *(unsigned*)&h;
}

// ---------------------------------------------------------------------------
// Kernel 0: Wf = Wo @ W1 (128x128) — no bias/nonlinearity between them.
__global__ __launch_bounds__(256) void k_wfuse(const float* __restrict__ Wo,
                                               const float* __restrict__ W1,
                                               float* __restrict__ Wf) {
    int idx = blockIdx.x * 256 + threadIdx.x;
    int r = idx >> 7, c = idx & 127;
    float acc = 0.f;
#pragma unroll 16
    for (int k = 0; k < 128; ++k) acc = fmaf(Wo[r * 128 + k], W1[k * 128 + c], acc);
    Wf[idx] = acc;
}

// ---------------------------------------------------------------------------
// Kernel 1: fused QKV projection. A-tile (64x128) staged ONCE, then the three
// weight tiles staged sequentially — feats traffic 3x lower than separate-z.
// grid = (E/64, 2). q stored f32 [E][128]; k/v stored bf16 PAIR-MAJOR:
//   kp[p][e][64] where slots 0..31 = head p, slots 32..63 = head p+2.
__global__ __launch_bounds__(256) void k_qkv(
    const float* __restrict__ feats,
    const float* __restrict__ Wq, const float* __restrict__ Wk,
    const float* __restrict__ Wv,
    float* __restrict__ qo, __hip_bfloat16* __restrict__ ko,
    __hip_bfloat16* __restrict__ vo) {
    __shared__ float As[64 * 132];
    __shared__ float Bs[128 * 68];

    const int t = threadIdx.x;
    const int row0 = blockIdx.x * 64;
    const int col0 = blockIdx.y * 64;
    const int tx = t & 15, ty = t >> 4;

    // Stage A tile (64x128) once.
    {
        const float4* src = (const float4*)(feats + (size_t)row0 * DIM);
#pragma unroll
        for (int p = 0; p < 8; ++p) {
            int id = t + p * 256;
            int r = id >> 5, c4 = id & 31;
            *(float4*)&As[r * 132 + c4 * 4] = src[r * 32 + c4];
        }
    }

    const float* Ws[3] = {Wq, Wk, Wv};
    for (int proj = 0; proj < 3; ++proj) {
        if (proj) __syncthreads();   // protect Bs from previous compute
        {
            const float* W = Ws[proj];
#pragma unroll
            for (int p = 0; p < 8; ++p) {
                int id = t + p * 256;
                int kk = id >> 4, c4 = id & 15;
                *(float4*)&Bs[kk * 68 + c4 * 4] =
                    *(const float4*)(W + kk * DIM + col0 + c4 * 4);
            }
        }
        __syncthreads();

        float acc[4][4] = {};
#pragma unroll 8
        for (int kk = 0; kk < 128; ++kk) {
            float a0 = As[(ty * 4 + 0) * 132 + kk];
            float a1 = As[(ty * 4 + 1) * 132 + kk];
            float a2 = As[(ty * 4 + 2) * 132 + kk];
            float a3 = As[(ty * 4 + 3) * 132 + kk];
            float4 b = *(float4*)&Bs[kk * 68 + tx * 4];
            acc[0][0] = fmaf(a0, b.x, acc[0][0]); acc[0][1] = fmaf(a0, b.y, acc[0][1]);
            acc[0][2] = fmaf(a0, b.z, acc[0][2]); acc[0][3] = fmaf(a0, b.w, acc[0][3]);
            acc[1][0] = fmaf(a1, b.x, acc[1][0]); acc[1][1] = fmaf(a1, b.y, acc[1][1]);
            acc[1][2] = fmaf(a1, b.z, acc[1][2]); acc[1][3] = fmaf(a1, b.w, acc[1][3]);
            acc[2][0] = fmaf(a2, b.x, acc[2][0]); acc[2][1] = fmaf(a2, b.y, acc[2][1]);
            acc[2][2] = fmaf(a2, b.z, acc[2][2]); acc[2][3] = fmaf(a2, b.w, acc[2][3]);
            acc[3][0] = fmaf(a3, b.x, acc[3][0]); acc[3][1] = fmaf(a3, b.y, acc[3][1]);
            acc[3][2] = fmaf(a3, b.z, acc[3][2]); acc[3][3] = fmaf(a3, b.w, acc[3][3]);
        }

        if (proj == 0) {
#pragma unroll
            for (int i = 0; i < 4; ++i) {
                float4 o = make_float4(acc[i][0], acc[i][1], acc[i][2], acc[i][3]);
                *(float4*)(qo + (size_t)(row0 + ty * 4 + i) * DIM + col0 + tx * 4) = o;
            }
        } else {
            __hip_bfloat16* dst = (proj == 1) ? ko : vo;
            const int c0 = col0 + tx * 4;            // 4-aligned within a head
            const int h = c0 >> 5;                   // head 0..3
            const int pr = h & 1;                    // pair index
            const int slot = ((h >> 1) << 5) + (c0 & 31);
#pragma unroll
            for (int i = 0; i < 4; ++i) {
                int row = row0 + ty * 4 + i;
                uint2 o;
                o.x = pk_bf2(acc[i][0], acc[i][1]);
                o.y = pk_bf2(acc[i][2], acc[i][3]);
                *(uint2*)(dst + ((size_t)pr * E_EDGES + row) * 64 + slot) = o;
            }
        }
    }
}

// ---------------------------------------------------------------------------
// Kernel 2: edge attention, one head-pair per launch (pass p -> heads p, p+2).
// Pair-major k/v: each gathered slice is a CONTIGUOUS 128B chunk, so the
// per-pass gather footprint is 4.2 MB (k) + 4.2 MB (v) — L2-resident.
// One 64-lane wave per edge; 4 edges per block.
// Phase 1: lane (g=lane>>5, n=lane&31) computes score for head p+2g of
// neighbor n (64B bf16 k-slice). Softmax via 32-lane shfl_xor.
// Phase 2: lane owns float4 col d4 of the 64-slot pair row; 4 lane-groups
// split the 32 neighbors; xor-16/32 combine. ctx overwrites q slices of the
// SAME heads (disjoint from the other pass).
__global__ __launch_bounds__(256) void k_attn_pass(
    float* qc,                                  // q in, ctx out (same buffer)
    const __hip_bfloat16* __restrict__ kp,
    const __hip_bfloat16* __restrict__ vp,
    const int* __restrict__ adj, int pass) {
    __shared__ float attn_s[4][64];
    __shared__ int adj_s[4][32];

    const int lane = threadIdx.x & 63;
    const int wid = threadIdx.x >> 6;
    const int e = blockIdx.x * 4 + wid;
    const int n = lane & 31;
    const int g = lane >> 5;

    if (lane < 32) adj_s[wid][lane] = adj[e * 32 + lane];

    // q slice for head pass+2g (32 floats) into registers.
    const float4* q4 = (const float4*)(qc + (size_t)e * DIM + (pass + 2 * g) * 32);
    float qa[32];
#pragma unroll
    for (int j = 0; j < 8; ++j) {
        float4 tA = q4[j];
        qa[j * 4 + 0] = tA.x; qa[j * 4 + 1] = tA.y;
        qa[j * 4 + 2] = tA.z; qa[j * 4 + 3] = tA.w;
    }

    const int row = adj_s[wid][n];
    const uint4* kr = (const uint4*)(kp + ((size_t)pass * E_EDGES + row) * 64 + g * 32);
    float s0 = 0.f;
#pragma unroll
    for (int j = 0; j < 4; ++j) {
        uint4 u = kr[j];
        s0 = fmaf(qa[j * 8 + 0], bflo(u.x), s0); s0 = fmaf(qa[j * 8 + 1], bfhi(u.x), s0);
        s0 = fmaf(qa[j * 8 + 2], bflo(u.y), s0); s0 = fmaf(qa[j * 8 + 3], bfhi(u.y), s0);
        s0 = fmaf(qa[j * 8 + 4], bflo(u.z), s0); s0 = fmaf(qa[j * 8 + 5], bfhi(u.z), s0);
        s0 = fmaf(qa[j * 8 + 6], bflo(u.w), s0); s0 = fmaf(qa[j * 8 + 7], bfhi(u.w), s0);
    }
    s0 *= 0.17677669529663689f;   // 1/sqrt(32)

    // Softmax over n within each 32-lane half.
    float m0 = s0;
#pragma unroll
    for (int off = 16; off; off >>= 1) m0 = fmaxf(m0, __shfl_xor(m0, off));
    float e0 = __expf(s0 - m0);
    float sum0 = e0;
#pragma unroll
    for (int off = 16; off; off >>= 1) sum0 += __shfl_xor(sum0, off);
    attn_s[wid][g * 32 + n] = e0 / sum0;

    // Phase 2: ctx (2 heads x 32) = attn @ v-slices.
    const int d4 = lane & 15;      // float4 column within the 64-slot pair row
    const int grp = lane >> 4;     // 4 groups x 8 neighbors
    const int gi = d4 >> 3;        // 0 -> head pass, 1 -> head pass+2
    float4 c = make_float4(0.f, 0.f, 0.f, 0.f);
#pragma unroll
    for (int i = 0; i < 8; ++i) {
        int nn = grp * 8 + i;
        int r2 = adj_s[wid][nn];
        float a = attn_s[wid][gi * 32 + nn];
        uint2 u = *(const uint2*)(vp + ((size_t)pass * E_EDGES + r2) * 64 + d4 * 4);
        c.x = fmaf(a, bflo(u.x), c.x); c.y = fmaf(a, bfhi(u.x), c.y);
        c.z = fmaf(a, bflo(u.y), c.z); c.w = fmaf(a, bfhi(u.y), c.w);
    }
    c.x += __shfl_xor(c.x, 16); c.y += __shfl_xor(c.y, 16);
    c.z += __shfl_xor(c.z, 16); c.w += __shfl_xor(c.w, 16);
    c.x += __shfl_xor(c.x, 32); c.y += __shfl_xor(c.y, 32);
    c.z += __shfl_xor(c.z, 32); c.w += __shfl_xor(c.w, 32);
    if (lane < 16) {
        int h2 = pass + 2 * gi;
        *(float4*)(qc + (size_t)e * DIM + h2 * 32 + (d4 & 7) * 4) = c;
    }
}

// ---------------------------------------------------------------------------
// Kernel 3: h = gelu_tanh(ctx @ Wf + b1); logits = h @ W2 + b2.
__global__ __launch_bounds__(256) void k_mlp(
    const float* __restrict__ ctx, const float* __restrict__ Wf,
    const float* __restrict__ b1, const float* __restrict__ W2,
    const float* __restrict__ b2, float* __restrict__ out) {
    __shared__ float cs[64 * 132];
    __shared__ float hs[64 * 132];
    __shared__ float w2s[1280];
    __shared__ float b2s[16];
    __shared__ float b1s[128];

    const int t = threadIdx.x;
    const int row0 = blockIdx.x * 64;

    {
        const float4* src = (const float4*)(ctx + (size_t)row0 * DIM);
#pragma unroll
        for (int p = 0; p < 8; ++p) {
            int id = t + p * 256;
            int r = id >> 5, c4 = id & 31;
            *(float4*)&cs[r * 132 + c4 * 4] = src[r * 32 + c4];
        }
    }
    for (int i = t; i < 1280; i += 256) w2s[i] = W2[i];
    if (t < 10) b2s[t] = b2[t];
    if (t < 128) b1s[t] = b1[t];
    __syncthreads();

    const int tx = t & 15, ty = t >> 4;
    float acc[4][8] = {};
#pragma unroll 4
    for (int kk = 0; kk < 128; ++kk) {
        float a0 = cs[(ty * 4 + 0) * 132 + kk];
        float a1 = cs[(ty * 4 + 1) * 132 + kk];
        float a2 = cs[(ty * 4 + 2) * 132 + kk];
        float a3 = cs[(ty * 4 + 3) * 132 + kk];
        float4 w0 = *(const float4*)(Wf + kk * DIM + tx * 8);
        float4 w1 = *(const float4*)(Wf + kk * DIM + tx * 8 + 4);
        float wj[8] = {w0.x, w0.y, w0.z, w0.w, w1.x, w1.y, w1.z, w1.w};
#pragma unroll
        for (int j = 0; j < 8; ++j) {
            acc[0][j] = fmaf(a0, wj[j], acc[0][j]);
            acc[1][j] = fmaf(a1, wj[j], acc[1][j]);
            acc[2][j] = fmaf(a2, wj[j], acc[2][j]);
            acc[3][j] = fmaf(a3, wj[j], acc[3][j]);
        }
    }
#pragma unroll
    for (int i = 0; i < 4; ++i) {
#pragma unroll
        for (int j = 0; j < 8; ++j) {
            int c = tx * 8 + j;
            float x = acc[i][j] + b1s[c];
            float u = 0.7978845608028654f * (x + 0.044715f * x * x * x);
            float ex = __expf(2.f * u);
            float th = 1.f - 2.f / (ex + 1.f);
            hs[(ty * 4 + i) * 132 + c] = 0.5f * x * (1.f + th);
        }
    }
    __syncthreads();

    for (int idx = t; idx < 640; idx += 256) {
        int r = idx / 10, c = idx - r * 10;
        float acc2 = b2s[c];
#pragma unroll 16
        for (int kk = 0; kk < 128; ++kk)
            acc2 = fmaf(hs[r * 132 + kk], w2s[kk * 10 + c], acc2);
        out[(size_t)(row0 + r) * 10 + c] = acc2;
    }
}

// ---------------------------------------------------------------------------
extern "C" void kernel_launch(void* const* d_in, const int* in_sizes, int n_in,
                              void* d_out, int out_size, void* d_ws, size_t ws_size,
                              hipStream_t stream) {
    const float* feats = (const float*)d_in[0];
    const float* Wq    = (const float*)d_in[1];
    const float* Wk    = (const float*)d_in[2];
    const float* Wv    = (const float*)d_in[3];
    const float* Wo    = (const float*)d_in[4];
    const float* W1    = (const float*)d_in[5];
    const float* b1    = (const float*)d_in[6];
    const float* W2    = (const float*)d_in[7];
    const float* b2    = (const float*)d_in[8];
    const int*   adj   = (const int*)d_in[9];
    float* out = (float*)d_out;

    float* ws = (float*)d_ws;
    const size_t ED = (size_t)E_EDGES * DIM;   // 4,194,304 elements
    float* qbuf = ws;                                   // f32 q, later ctx
    __hip_bfloat16* kbuf = (__hip_bfloat16*)(ws + ED);  // bf16 k, pair-major
    __hip_bfloat16* vbuf = kbuf + ED;                   // bf16 v, pair-major
    float* wf = (float*)(vbuf + ED);                    // 16384 f32

    k_wfuse<<<64, 256, 0, stream>>>(Wo, W1, wf);
    k_qkv<<<dim3(E_EDGES / 64, 2), 256, 0, stream>>>(feats, Wq, Wk, Wv,
                                                     qbuf, kbuf, vbuf);
    k_attn_pass<<<E_EDGES / 4, 256, 0, stream>>>(qbuf, kbuf, vbuf, adj, 0);
    k_attn_pass<<<E_EDGES / 4, 256, 0, stream>>>(qbuf, kbuf, vbuf, adj, 1);
    k_mlp<<<E_EDGES / 64, 256, 0, stream>>>(qbuf, wf, b1, W2, b2, out);
}

// Round 4
// 125.627 us; speedup vs baseline: 2.0121x; 1.2006x over previous
//
#include <hip/hip_runtime.h>
#include <hip/hip_bf16.h>

// Problem constants: E=32768, K=32, D=128, H=4, dh=32, C=10
constexpr int E_EDGES = 32768;
constexpr int DIM = 128;

using bf16x8 = __attribute__((ext_vector_type(8))) short;   // MFMA A/B frag
using f32x4  = __attribute__((ext_vector_type(4))) float;   // MFMA C/D frag

// bf16 (upper 16 bits of f32) unpack helpers
__device__ inline float bflo(unsigned u) { return __uint_as_float(u << 16); }
__device__ inline float bfhi(unsigned u) { return __uint_as_float(u & 0xffff0000u); }
__device__ inline unsigned pk_bf2(float a, float b) {
    __hip_bfloat162 h = __float22bfloat162_rn(make_float2(a, b));
    return *(unsigned*)&h;
}

// ---------------------------------------------------------------------------
// Kernel P: Wt[proj][n][k] = bf16(W_proj[k][n]) — transposed bf16 weights so
// the GEMM's B-frag reads are contiguous ds_read_b128 (B^T idiom, m91).
__global__ __launch_bounds__(256) void k_prep(
    const float* __restrict__ Wq, const float* __restrict__ Wk,
    const float* __restrict__ Wv, __hip_bfloat16* __restrict__ Wt) {
    const float* W = (blockIdx.x == 0) ? Wq : (blockIdx.x == 1) ? Wk : Wv;
    __hip_bfloat16* dst = Wt + blockIdx.x * 16384;
    const int t = threadIdx.x;
#pragma unroll
    for (int i = 0; i < 8; ++i) {
        int idx = i * 2048 + t * 8;
        int k = idx >> 7, n0 = idx & 127;
        float4 f0 = *(const float4*)(W + k * 128 + n0);       // coalesced read
        float4 f1 = *(const float4*)(W + k * 128 + n0 + 4);
        float f[8] = {f0.x, f0.y, f0.z, f0.w, f1.x, f1.y, f1.z, f1.w};
#pragma unroll
        for (int j = 0; j < 8; ++j)
            dst[(n0 + j) * 128 + k] = __float2bfloat16(f[j]); // scattered 2B store
    }
}

// ---------------------------------------------------------------------------
// Kernel 0: Wf = Wo @ W1 (128x128, f32) — no bias/nonlinearity between them.
__global__ __launch_bounds__(256) void k_wfuse(const float* __restrict__ Wo,
                                               const float* __restrict__ W1,
                                               float* __restrict__ Wf) {
    int idx = blockIdx.x * 256 + threadIdx.x;
    int r = idx >> 7, c = idx & 127;
    float acc = 0.f;
#pragma unroll 16
    for (int k = 0; k < 128; ++k) acc = fmaf(Wo[r * 128 + k], W1[k * 128 + c], acc);
    Wf[idx] = acc;
}

// ---------------------------------------------------------------------------
// Kernel 1: QKV projection via bf16 MFMA. 128x128 tile per block, 4 waves
// (2x2, 64x64 each), K=128 in 4 steps of 32. A (feats) converted f32->bf16
// during staging into XOR-swizzled LDS; A-frags loaded ONCE into registers
// and reused across all 3 projections. B staged per projection from the
// pre-transposed bf16 Wt. q stored f32 [E][128]; k/v stored bf16 pair-major
// kp[pr][e][64] (head h -> pr=h&1, slot=((h>>1)<<5)+(c&31)).
__global__ __launch_bounds__(256) void k_qkv(
    const float* __restrict__ feats, const __hip_bfloat16* __restrict__ Wt,
    float* __restrict__ qo, __hip_bfloat16* __restrict__ ko,
    __hip_bfloat16* __restrict__ vo) {
    __shared__ short Als[16384];   // 128x128 bf16, swizzled: elem ^= (row&7)<<3
    __shared__ short Bls[16384];   // 128(n) x 128(k) bf16, same swizzle

    const int t = threadIdx.x;
    const int lane = t & 63;
    const int w = t >> 6;
    const int wm = w >> 1, wn = w & 1;       // 2x2 wave grid, 64x64 per wave
    const int row0 = blockIdx.x * 128;

    // Stage A tile: coalesced f32 reads, cvt to bf16, swizzled ds_write_b128.
#pragma unroll
    for (int i = 0; i < 8; ++i) {
        int idx = i * 2048 + t * 8;
        int r = idx >> 7, k0 = idx & 127;
        float4 f0 = *(const float4*)(feats + (size_t)(row0 + r) * DIM + k0);
        float4 f1 = *(const float4*)(feats + (size_t)(row0 + r) * DIM + k0 + 4);
        uint4 o = make_uint4(pk_bf2(f0.x, f0.y), pk_bf2(f0.z, f0.w),
                             pk_bf2(f1.x, f1.y), pk_bf2(f1.z, f1.w));
        *(uint4*)&Als[(r * 128 + k0) ^ ((r & 7) << 3)] = o;
    }
    // Stage B for proj 0 (plain bf16 copy, swizzled).
#pragma unroll
    for (int i = 0; i < 8; ++i) {
        int idx = i * 2048 + t * 8;
        int n = idx >> 7, k0 = idx & 127;
        uint4 v = *(const uint4*)(Wt + n * 128 + k0);
        *(uint4*)&Bls[(n * 128 + k0) ^ ((n & 7) << 3)] = v;
    }
    __syncthreads();

    // A-frags into registers, once. A lane map: row=l&15, k=(l>>4)*8+j.
    bf16x8 afr[4][4];
#pragma unroll
    for (int m = 0; m < 4; ++m)
#pragma unroll
        for (int ks = 0; ks < 4; ++ks) {
            int r = wm * 64 + m * 16 + (lane & 15);
            int kb = ks * 32 + (lane >> 4) * 8;
            afr[m][ks] = *(bf16x8*)&Als[(r * 128 + kb) ^ ((r & 7) << 3)];
        }

    for (int proj = 0; proj < 3; ++proj) {
        f32x4 acc[4][4];
#pragma unroll
        for (int m = 0; m < 4; ++m)
#pragma unroll
            for (int n = 0; n < 4; ++n) acc[m][n] = (f32x4){0.f, 0.f, 0.f, 0.f};

#pragma unroll
        for (int ks = 0; ks < 4; ++ks) {
            bf16x8 bfr[4];
#pragma unroll
            for (int n = 0; n < 4; ++n) {
                int nn = wn * 64 + n * 16 + (lane & 15);
                int kb = ks * 32 + (lane >> 4) * 8;
                bfr[n] = *(bf16x8*)&Bls[(nn * 128 + kb) ^ ((nn & 7) << 3)];
            }
#pragma unroll
            for (int m = 0; m < 4; ++m)
#pragma unroll
                for (int n = 0; n < 4; ++n)
                    acc[m][n] = __builtin_amdgcn_mfma_f32_16x16x32_bf16(
                        afr[m][ks], bfr[n], acc[m][n], 0, 0, 0);
        }

        // Epilogue. C/D map: row=(l>>4)*4+r, col=l&15 (m89-verified).
        if (proj == 0) {
#pragma unroll
            for (int m = 0; m < 4; ++m) {
                int rb = row0 + wm * 64 + m * 16 + (lane >> 4) * 4;
#pragma unroll
                for (int n = 0; n < 4; ++n) {
                    int c = wn * 64 + n * 16 + (lane & 15);
#pragma unroll
                    for (int r = 0; r < 4; ++r)
                        qo[(size_t)(rb + r) * DIM + c] = acc[m][n][r];
                }
            }
        } else {
            __hip_bfloat16* dst = (proj == 1) ? ko : vo;
#pragma unroll
            for (int n = 0; n < 4; ++n) {
                int c = wn * 64 + n * 16 + (lane & 15);
                int h = c >> 5, pr = h & 1;
                int slot = ((h >> 1) << 5) + (c & 31);
                size_t base = (size_t)pr * E_EDGES * 64 + slot;
#pragma unroll
                for (int m = 0; m < 4; ++m) {
                    int rb = row0 + wm * 64 + m * 16 + (lane >> 4) * 4;
#pragma unroll
                    for (int r = 0; r < 4; ++r)
                        dst[base + (size_t)(rb + r) * 64] =
                            __float2bfloat16(acc[m][n][r]);
                }
            }
        }

        if (proj < 2) {
            __syncthreads();   // all waves done reading Bls
#pragma unroll
            for (int i = 0; i < 8; ++i) {
                int idx = i * 2048 + t * 8;
                int n = idx >> 7, k0 = idx & 127;
                uint4 v = *(const uint4*)(Wt + (proj + 1) * 16384 + n * 128 + k0);
                *(uint4*)&Bls[(n * 128 + k0) ^ ((n & 7) << 3)] = v;
            }
            __syncthreads();
        }
    }
}

// ---------------------------------------------------------------------------
// Kernel 2: edge attention, one head-pair per launch (pass p -> heads p, p+2).
// Pair-major k/v: gathered slice is a contiguous 128B chunk; per-pass gather
// footprint 8.4 MB. One 64-lane wave per edge; 4 edges per block.
__global__ __launch_bounds__(256) void k_attn_pass(
    float* qc,                                  // q in, ctx out (same buffer)
    const __hip_bfloat16* __restrict__ kp,
    const __hip_bfloat16* __restrict__ vp,
    const int* __restrict__ adj, int pass) {
    __shared__ float attn_s[4][64];
    __shared__ int adj_s[4][32];

    const int lane = threadIdx.x & 63;
    const int wid = threadIdx.x >> 6;
    const int e = blockIdx.x * 4 + wid;
    const int n = lane & 31;
    const int g = lane >> 5;

    if (lane < 32) adj_s[wid][lane] = adj[e * 32 + lane];

    const float4* q4 = (const float4*)(qc + (size_t)e * DIM + (pass + 2 * g) * 32);
    float qa[32];
#pragma unroll
    for (int j = 0; j < 8; ++j) {
        float4 tA = q4[j];
        qa[j * 4 + 0] = tA.x; qa[j * 4 + 1] = tA.y;
        qa[j * 4 + 2] = tA.z; qa[j * 4 + 3] = tA.w;
    }

    const int row = adj_s[wid][n];
    const uint4* kr = (const uint4*)(kp + ((size_t)pass * E_EDGES + row) * 64 + g * 32);
    float s0 = 0.f;
#pragma unroll
    for (int j = 0; j < 4; ++j) {
        uint4 u = kr[j];
        s0 = fmaf(qa[j * 8 + 0], bflo(u.x), s0); s0 = fmaf(qa[j * 8 + 1], bfhi(u.x), s0);
        s0 = fmaf(qa[j * 8 + 2], bflo(u.y), s0); s0 = fmaf(qa[j * 8 + 3], bfhi(u.y), s0);
        s0 = fmaf(qa[j * 8 + 4], bflo(u.z), s0); s0 = fmaf(qa[j * 8 + 5], bfhi(u.z), s0);
        s0 = fmaf(qa[j * 8 + 6], bflo(u.w), s0); s0 = fmaf(qa[j * 8 + 7], bfhi(u.w), s0);
    }
    s0 *= 0.17677669529663689f;   // 1/sqrt(32)

    float m0 = s0;
#pragma unroll
    for (int off = 16; off; off >>= 1) m0 = fmaxf(m0, __shfl_xor(m0, off));
    float e0 = __expf(s0 - m0);
    float sum0 = e0;
#pragma unroll
    for (int off = 16; off; off >>= 1) sum0 += __shfl_xor(sum0, off);
    attn_s[wid][g * 32 + n] = e0 / sum0;

    const int d4 = lane & 15;
    const int grp = lane >> 4;
    const int gi = d4 >> 3;
    float4 c = make_float4(0.f, 0.f, 0.f, 0.f);
#pragma unroll
    for (int i = 0; i < 8; ++i) {
        int nn = grp * 8 + i;
        int r2 = adj_s[wid][nn];
        float a = attn_s[wid][gi * 32 + nn];
        uint2 u = *(const uint2*)(vp + ((size_t)pass * E_EDGES + r2) * 64 + d4 * 4);
        c.x = fmaf(a, bflo(u.x), c.x); c.y = fmaf(a, bfhi(u.x), c.y);
        c.z = fmaf(a, bflo(u.y), c.z); c.w = fmaf(a, bfhi(u.y), c.w);
    }
    c.x += __shfl_xor(c.x, 16); c.y += __shfl_xor(c.y, 16);
    c.z += __shfl_xor(c.z, 16); c.w += __shfl_xor(c.w, 16);
    c.x += __shfl_xor(c.x, 32); c.y += __shfl_xor(c.y, 32);
    c.z += __shfl_xor(c.z, 32); c.w += __shfl_xor(c.w, 32);
    if (lane < 16) {
        int h2 = pass + 2 * gi;
        *(float4*)(qc + (size_t)e * DIM + h2 * 32 + (d4 & 7) * 4) = c;
    }
}

// ---------------------------------------------------------------------------
// Kernel 3: h = gelu_tanh(ctx @ Wf + b1); logits = h @ W2 + b2. (f32)
__global__ __launch_bounds__(256) void k_mlp(
    const float* __restrict__ ctx, const float* __restrict__ Wf,
    const float* __restrict__ b1, const float* __restrict__ W2,
    const float* __restrict__ b2, float* __restrict__ out) {
    __shared__ float cs[64 * 132];
    __shared__ float hs[64 * 132];
    __shared__ float w2s[1280];
    __shared__ float b2s[16];
    __shared__ float b1s[128];

    const int t = threadIdx.x;
    const int row0 = blockIdx.x * 64;

    {
        const float4* src = (const float4*)(ctx + (size_t)row0 * DIM);
#pragma unroll
        for (int p = 0; p < 8; ++p) {
            int id = t + p * 256;
            int r = id >> 5, c4 = id & 31;
            *(float4*)&cs[r * 132 + c4 * 4] = src[r * 32 + c4];
        }
    }
    for (int i = t; i < 1280; i += 256) w2s[i] = W2[i];
    if (t < 10) b2s[t] = b2[t];
    if (t < 128) b1s[t] = b1[t];
    __syncthreads();

    const int tx = t & 15, ty = t >> 4;
    float acc[4][8] = {};
#pragma unroll 4
    for (int kk = 0; kk < 128; ++kk) {
        float a0 = cs[(ty * 4 + 0) * 132 + kk];
        float a1 = cs[(ty * 4 + 1) * 132 + kk];
        float a2 = cs[(ty * 4 + 2) * 132 + kk];
        float a3 = cs[(ty * 4 + 3) * 132 + kk];
        float4 w0 = *(const float4*)(Wf + kk * DIM + tx * 8);
        float4 w1 = *(const float4*)(Wf + kk * DIM + tx * 8 + 4);
        float wj[8] = {w0.x, w0.y, w0.z, w0.w, w1.x, w1.y, w1.z, w1.w};
#pragma unroll
        for (int j = 0; j < 8; ++j) {
            acc[0][j] = fmaf(a0, wj[j], acc[0][j]);
            acc[1][j] = fmaf(a1, wj[j], acc[1][j]);
            acc[2][j] = fmaf(a2, wj[j], acc[2][j]);
            acc[3][j] = fmaf(a3, wj[j], acc[3][j]);
        }
    }
#pragma unroll
    for (int i = 0; i < 4; ++i) {
#pragma unroll
        for (int j = 0; j < 8; ++j) {
            int c = tx * 8 + j;
            float x = acc[i][j] + b1s[c];
            float u = 0.7978845608028654f * (x + 0.044715f * x * x * x);
            float ex = __expf(2.f * u);
            float th = 1.f - 2.f / (ex + 1.f);
            hs[(ty * 4 + i) * 132 + c] = 0.5f * x * (1.f + th);
        }
    }
    __syncthreads();

    for (int idx = t; idx < 640; idx += 256) {
        int r = idx / 10, c = idx - r * 10;
        float acc2 = b2s[c];
#pragma unroll 16
        for (int kk = 0; kk < 128; ++kk)
            acc2 = fmaf(hs[r * 132 + kk], w2s[kk * 10 + c], acc2);
        out[(size_t)(row0 + r) * 10 + c] = acc2;
    }
}

// ---------------------------------------------------------------------------
extern "C" void kernel_launch(void* const* d_in, const int* in_sizes, int n_in,
                              void* d_out, int out_size, void* d_ws, size_t ws_size,
                              hipStream_t stream) {
    const float* feats = (const float*)d_in[0];
    const float* Wq    = (const float*)d_in[1];
    const float* Wk    = (const float*)d_in[2];
    const float* Wv    = (const float*)d_in[3];
    const float* Wo    = (const float*)d_in[4];
    const float* W1    = (const float*)d_in[5];
    const float* b1    = (const float*)d_in[6];
    const float* W2    = (const float*)d_in[7];
    const float* b2    = (const float*)d_in[8];
    const int*   adj   = (const int*)d_in[9];
    float* out = (float*)d_out;

    float* ws = (float*)d_ws;
    const size_t ED = (size_t)E_EDGES * DIM;   // 4,194,304 elements
    float* qbuf = ws;                                   // f32 q, later ctx
    __hip_bfloat16* kbuf = (__hip_bfloat16*)(ws + ED);  // bf16 k, pair-major
    __hip_bfloat16* vbuf = kbuf + ED;                   // bf16 v, pair-major
    float* wf = (float*)(vbuf + ED);                    // 16384 f32
    __hip_bfloat16* wt = (__hip_bfloat16*)(wf + 16384); // 3*16384 bf16

    k_prep<<<3, 256, 0, stream>>>(Wq, Wk, Wv, wt);
    k_wfuse<<<64, 256, 0, stream>>>(Wo, W1, wf);
    k_qkv<<<E_EDGES / 128, 256, 0, stream>>>(feats, wt, qbuf, kbuf, vbuf);
    k_attn_pass<<<E_EDGES / 4, 256, 0, stream>>>(qbuf, kbuf, vbuf, adj, 0);
    k_attn_pass<<<E_EDGES / 4, 256, 0, stream>>>(qbuf, kbuf, vbuf, adj, 1);
    k_mlp<<<E_EDGES / 64, 256, 0, stream>>>(qbuf, wf, b1, W2, b2, out);
}

// Round 6
// 110.947 us; speedup vs baseline: 2.2783x; 1.1323x over previous
//
#include <hip/hip_runtime.h>
#include <hip/hip_bf16.h>

// Problem constants: E=32768, K=32, D=128, H=4, dh=32, C=10
constexpr int E_EDGES = 32768;
constexpr int DIM = 128;

using bf16x8 = __attribute__((ext_vector_type(8))) short;   // MFMA A/B frag
using f32x4  = __attribute__((ext_vector_type(4))) float;   // MFMA C/D frag

// bf16 (upper 16 bits of f32) unpack helpers
__device__ inline float bflo(unsigned u) { return __uint_as_float(u << 16); }
__device__ inline float bfhi(unsigned u) { return __uint_as_float(u & 0xffff0000u); }
__device__ inline unsigned pk_bf2(float a, float b) {
    __hip_bfloat162 h = __float22bfloat162_rn(make_float2(a, b));
    return *(unsigned*)&h;
}

// ---------------------------------------------------------------------------
// Kernel P (grid=67): blocks 0-2: Wt[proj][n][k] = bf16(W_proj[k][n]).
// Blocks 3-66: Wf = Wo @ W1, stored transposed bf16: wft[n][k] = bf16(Wf[k][n]).
__global__ __launch_bounds__(256) void k_prep(
    const float* __restrict__ Wq, const float* __restrict__ Wk,
    const float* __restrict__ Wv, const float* __restrict__ Wo,
    const float* __restrict__ W1, __hip_bfloat16* __restrict__ Wt,
    __hip_bfloat16* __restrict__ wft) {
    const int b = blockIdx.x;
    const int t = threadIdx.x;
    if (b < 3) {
        const float* W = (b == 0) ? Wq : (b == 1) ? Wk : Wv;
        __hip_bfloat16* dst = Wt + b * 16384;
#pragma unroll
        for (int i = 0; i < 8; ++i) {
            int idx = i * 2048 + t * 8;
            int k = idx >> 7, n0 = idx & 127;
            float4 f0 = *(const float4*)(W + k * 128 + n0);
            float4 f1 = *(const float4*)(W + k * 128 + n0 + 4);
            float f[8] = {f0.x, f0.y, f0.z, f0.w, f1.x, f1.y, f1.z, f1.w};
#pragma unroll
            for (int j = 0; j < 8; ++j)
                dst[(n0 + j) * 128 + k] = __float2bfloat16(f[j]);
        }
    } else {
        int idx = (b - 3) * 256 + t;        // 0..16383
        int r = idx >> 7, c = idx & 127;    // Wf row r, col c
        float acc = 0.f;
#pragma unroll 16
        for (int k = 0; k < 128; ++k)
            acc = fmaf(Wo[r * 128 + k], W1[k * 128 + c], acc);
        wft[c * 128 + r] = __float2bfloat16(acc);
    }
}

// ---------------------------------------------------------------------------
// Kernel 1: QKV projection via bf16 MFMA. 128x128 tile per block, 4 waves
// (2x2, 64x64 each), K=128 in 4 steps of 32. A-frags loaded once, reused for
// all 3 projections. q stored f32 [E][128]; k/v stored bf16 pair-major
// kp[pr][e][64] (head h -> pr=h&1, slot=((h>>1)<<5)+(c&31)).
__global__ __launch_bounds__(256) void k_qkv(
    const float* __restrict__ feats, const __hip_bfloat16* __restrict__ Wt,
    float* __restrict__ qo, __hip_bfloat16* __restrict__ ko,
    __hip_bfloat16* __restrict__ vo) {
    __shared__ short Als[16384];   // 128x128 bf16, swizzled: elem ^= (row&7)<<3
    __shared__ short Bls[16384];

    const int t = threadIdx.x;
    const int lane = t & 63;
    const int w = t >> 6;
    const int wm = w >> 1, wn = w & 1;
    const int row0 = blockIdx.x * 128;

#pragma unroll
    for (int i = 0; i < 8; ++i) {
        int idx = i * 2048 + t * 8;
        int r = idx >> 7, k0 = idx & 127;
        float4 f0 = *(const float4*)(feats + (size_t)(row0 + r) * DIM + k0);
        float4 f1 = *(const float4*)(feats + (size_t)(row0 + r) * DIM + k0 + 4);
        uint4 o = make_uint4(pk_bf2(f0.x, f0.y), pk_bf2(f0.z, f0.w),
                             pk_bf2(f1.x, f1.y), pk_bf2(f1.z, f1.w));
        *(uint4*)&Als[(r * 128 + k0) ^ ((r & 7) << 3)] = o;
    }
#pragma unroll
    for (int i = 0; i < 8; ++i) {
        int idx = i * 2048 + t * 8;
        int n = idx >> 7, k0 = idx & 127;
        uint4 v = *(const uint4*)(Wt + n * 128 + k0);
        *(uint4*)&Bls[(n * 128 + k0) ^ ((n & 7) << 3)] = v;
    }
    __syncthreads();

    bf16x8 afr[4][4];
#pragma unroll
    for (int m = 0; m < 4; ++m)
#pragma unroll
        for (int ks = 0; ks < 4; ++ks) {
            int r = wm * 64 + m * 16 + (lane & 15);
            int kb = ks * 32 + (lane >> 4) * 8;
            afr[m][ks] = *(bf16x8*)&Als[(r * 128 + kb) ^ ((r & 7) << 3)];
        }

    for (int proj = 0; proj < 3; ++proj) {
        f32x4 acc[4][4];
#pragma unroll
        for (int m = 0; m < 4; ++m)
#pragma unroll
            for (int n = 0; n < 4; ++n) acc[m][n] = (f32x4){0.f, 0.f, 0.f, 0.f};

#pragma unroll
        for (int ks = 0; ks < 4; ++ks) {
            bf16x8 bfr[4];
#pragma unroll
            for (int n = 0; n < 4; ++n) {
                int nn = wn * 64 + n * 16 + (lane & 15);
                int kb = ks * 32 + (lane >> 4) * 8;
                bfr[n] = *(bf16x8*)&Bls[(nn * 128 + kb) ^ ((nn & 7) << 3)];
            }
#pragma unroll
            for (int m = 0; m < 4; ++m)
#pragma unroll
                for (int n = 0; n < 4; ++n)
                    acc[m][n] = __builtin_amdgcn_mfma_f32_16x16x32_bf16(
                        afr[m][ks], bfr[n], acc[m][n], 0, 0, 0);
        }

        if (proj == 0) {
#pragma unroll
            for (int m = 0; m < 4; ++m) {
                int rb = row0 + wm * 64 + m * 16 + (lane >> 4) * 4;
#pragma unroll
                for (int n = 0; n < 4; ++n) {
                    int c = wn * 64 + n * 16 + (lane & 15);
#pragma unroll
                    for (int r = 0; r < 4; ++r)
                        qo[(size_t)(rb + r) * DIM + c] = acc[m][n][r];
                }
            }
        } else {
            __hip_bfloat16* dst = (proj == 1) ? ko : vo;
#pragma unroll
            for (int n = 0; n < 4; ++n) {
                int c = wn * 64 + n * 16 + (lane & 15);
                int h = c >> 5, pr = h & 1;
                int slot = ((h >> 1) << 5) + (c & 31);
                size_t base = (size_t)pr * E_EDGES * 64 + slot;
#pragma unroll
                for (int m = 0; m < 4; ++m) {
                    int rb = row0 + wm * 64 + m * 16 + (lane >> 4) * 4;
#pragma unroll
                    for (int r = 0; r < 4; ++r)
                        dst[base + (size_t)(rb + r) * 64] =
                            __float2bfloat16(acc[m][n][r]);
                }
            }
        }

        if (proj < 2) {
            __syncthreads();
#pragma unroll
            for (int i = 0; i < 8; ++i) {
                int idx = i * 2048 + t * 8;
                int n = idx >> 7, k0 = idx & 127;
                uint4 v = *(const uint4*)(Wt + (proj + 1) * 16384 + n * 128 + k0);
                *(uint4*)&Bls[(n * 128 + k0) ^ ((n & 7) << 3)] = v;
            }
            __syncthreads();
        }
    }
}

// ---------------------------------------------------------------------------
// Kernel 2: edge attention, one head-pair per launch (pass p -> heads p, p+2).
// ctx written as bf16 to ctxb (consumed by the MFMA MLP).
__global__ __launch_bounds__(256) void k_attn_pass(
    const float* __restrict__ qc, const __hip_bfloat16* __restrict__ kp,
    const __hip_bfloat16* __restrict__ vp, const int* __restrict__ adj,
    __hip_bfloat16* __restrict__ ctxb, int pass) {
    __shared__ float attn_s[4][64];
    __shared__ int adj_s[4][32];

    const int lane = threadIdx.x & 63;
    const int wid = threadIdx.x >> 6;
    const int e = blockIdx.x * 4 + wid;
    const int n = lane & 31;
    const int g = lane >> 5;

    if (lane < 32) adj_s[wid][lane] = adj[e * 32 + lane];

    const float4* q4 = (const float4*)(qc + (size_t)e * DIM + (pass + 2 * g) * 32);
    float qa[32];
#pragma unroll
    for (int j = 0; j < 8; ++j) {
        float4 tA = q4[j];
        qa[j * 4 + 0] = tA.x; qa[j * 4 + 1] = tA.y;
        qa[j * 4 + 2] = tA.z; qa[j * 4 + 3] = tA.w;
    }

    const int row = adj_s[wid][n];
    const uint4* kr = (const uint4*)(kp + ((size_t)pass * E_EDGES + row) * 64 + g * 32);
    float s0 = 0.f;
#pragma unroll
    for (int j = 0; j < 4; ++j) {
        uint4 u = kr[j];
        s0 = fmaf(qa[j * 8 + 0], bflo(u.x), s0); s0 = fmaf(qa[j * 8 + 1], bfhi(u.x), s0);
        s0 = fmaf(qa[j * 8 + 2], bflo(u.y), s0); s0 = fmaf(qa[j * 8 + 3], bfhi(u.y), s0);
        s0 = fmaf(qa[j * 8 + 4], bflo(u.z), s0); s0 = fmaf(qa[j * 8 + 5], bfhi(u.z), s0);
        s0 = fmaf(qa[j * 8 + 6], bflo(u.w), s0); s0 = fmaf(qa[j * 8 + 7], bfhi(u.w), s0);
    }
    s0 *= 0.17677669529663689f;   // 1/sqrt(32)

    float m0 = s0;
#pragma unroll
    for (int off = 16; off; off >>= 1) m0 = fmaxf(m0, __shfl_xor(m0, off));
    float e0 = __expf(s0 - m0);
    float sum0 = e0;
#pragma unroll
    for (int off = 16; off; off >>= 1) sum0 += __shfl_xor(sum0, off);
    attn_s[wid][g * 32 + n] = e0 / sum0;

    const int d4 = lane & 15;
    const int grp = lane >> 4;
    const int gi = d4 >> 3;
    float4 c = make_float4(0.f, 0.f, 0.f, 0.f);
#pragma unroll
    for (int i = 0; i < 8; ++i) {
        int nn = grp * 8 + i;
        int r2 = adj_s[wid][nn];
        float a = attn_s[wid][gi * 32 + nn];
        uint2 u = *(const uint2*)(vp + ((size_t)pass * E_EDGES + r2) * 64 + d4 * 4);
        c.x = fmaf(a, bflo(u.x), c.x); c.y = fmaf(a, bfhi(u.x), c.y);
        c.z = fmaf(a, bflo(u.y), c.z); c.w = fmaf(a, bfhi(u.y), c.w);
    }
    c.x += __shfl_xor(c.x, 16); c.y += __shfl_xor(c.y, 16);
    c.z += __shfl_xor(c.z, 16); c.w += __shfl_xor(c.w, 16);
    c.x += __shfl_xor(c.x, 32); c.y += __shfl_xor(c.y, 32);
    c.z += __shfl_xor(c.z, 32); c.w += __shfl_xor(c.w, 32);
    if (lane < 16) {
        int h2 = pass + 2 * gi;
        uint2 o;
        o.x = pk_bf2(c.x, c.y);
        o.y = pk_bf2(c.z, c.w);
        *(uint2*)(ctxb + (size_t)e * DIM + h2 * 32 + (d4 & 7) * 4) = o;
    }
}

// ---------------------------------------------------------------------------
// Kernel 3: MLP via bf16 MFMA. Per block: 128 rows, 4 waves (2x2).
// h = gelu_tanh(ctx @ Wf + b1) computed with MFMA (ctx bf16, wft = Wf^T bf16),
// h re-staged bf16 into the A-tile LDS, then logits = h @ W2 + b2 (f32 vector).
__global__ __launch_bounds__(256) void k_mlp(
    const __hip_bfloat16* __restrict__ ctxb, const __hip_bfloat16* __restrict__ wft,
    const float* __restrict__ b1, const float* __restrict__ W2,
    const float* __restrict__ b2, float* __restrict__ out) {
    __shared__ short Als[16384];   // A tile, then reused for h (bf16, swizzled)
    __shared__ short Bls[16384];
    __shared__ float w2s[1280];
    __shared__ float b1s[128];
    __shared__ float b2s[16];

    const int t = threadIdx.x;
    const int lane = t & 63;
    const int w = t >> 6;
    const int wm = w >> 1, wn = w & 1;
    const int row0 = blockIdx.x * 128;

#pragma unroll
    for (int i = 0; i < 8; ++i) {   // A: 16384 bf16 = 2048 uint4 (FIXED: 8 iters)
        int idx = i * 2048 + t * 8;
        int r = idx >> 7, k0 = idx & 127;
        uint4 v = *(const uint4*)(ctxb + (size_t)(row0 + r) * DIM + k0);
        *(uint4*)&Als[(r * 128 + k0) ^ ((r & 7) << 3)] = v;
    }
#pragma unroll
    for (int i = 0; i < 8; ++i) {   // B: wft (FIXED: 8 iters)
        int idx = i * 2048 + t * 8;
        int n = idx >> 7, k0 = idx & 127;
        uint4 v = *(const uint4*)(wft + n * 128 + k0);
        *(uint4*)&Bls[(n * 128 + k0) ^ ((n & 7) << 3)] = v;
    }
    for (int i = t; i < 1280; i += 256) w2s[i] = W2[i];
    if (t < 128) b1s[t] = b1[t];
    if (t < 10) b2s[t] = b2[t];
    __syncthreads();

    f32x4 acc[4][4];
#pragma unroll
    for (int m = 0; m < 4; ++m)
#pragma unroll
        for (int n = 0; n < 4; ++n) acc[m][n] = (f32x4){0.f, 0.f, 0.f, 0.f};

#pragma unroll
    for (int ks = 0; ks < 4; ++ks) {
        bf16x8 afr[4], bfr[4];
#pragma unroll
        for (int m = 0; m < 4; ++m) {
            int r = wm * 64 + m * 16 + (lane & 15);
            int kb = ks * 32 + (lane >> 4) * 8;
            afr[m] = *(bf16x8*)&Als[(r * 128 + kb) ^ ((r & 7) << 3)];
        }
#pragma unroll
        for (int n = 0; n < 4; ++n) {
            int nn = wn * 64 + n * 16 + (lane & 15);
            int kb = ks * 32 + (lane >> 4) * 8;
            bfr[n] = *(bf16x8*)&Bls[(nn * 128 + kb) ^ ((nn & 7) << 3)];
        }
#pragma unroll
        for (int m = 0; m < 4; ++m)
#pragma unroll
            for (int n = 0; n < 4; ++n)
                acc[m][n] = __builtin_amdgcn_mfma_f32_16x16x32_bf16(
                    afr[m], bfr[n], acc[m][n], 0, 0, 0);
    }

    __syncthreads();   // done reading Als; reuse it for h
#pragma unroll
    for (int m = 0; m < 4; ++m) {
        int lr0 = wm * 64 + m * 16 + (lane >> 4) * 4;   // local row base
#pragma unroll
        for (int n = 0; n < 4; ++n) {
            int c = wn * 64 + n * 16 + (lane & 15);
            float bc = b1s[c];
#pragma unroll
            for (int r = 0; r < 4; ++r) {
                float x = acc[m][n][r] + bc;
                float u = 0.7978845608028654f * (x + 0.044715f * x * x * x);
                float ex = __expf(2.f * u);
                float th = 1.f - 2.f / (ex + 1.f);
                float h = 0.5f * x * (1.f + th);
                int lr = lr0 + r;
                Als[(lr * 128 + c) ^ ((lr & 7) << 3)] =
                    (short)(__bfloat16_as_ushort(__float2bfloat16(h)));
            }
        }
    }
    __syncthreads();

    // logits: 1280 outputs; thread t -> row t>>1, cols (t&1)*5 .. +5.
    {
        int r = t >> 1;
        int c0 = (t & 1) * 5;
        float a0 = b2s[c0], a1 = b2s[c0 + 1], a2 = b2s[c0 + 2],
              a3 = b2s[c0 + 3], a4 = b2s[c0 + 4];
#pragma unroll 8
        for (int kk = 0; kk < 128; ++kk) {
            float hv = __uint_as_float(
                ((unsigned)(unsigned short)Als[(r * 128 + kk) ^ ((r & 7) << 3)]) << 16);
            const float* wrow = &w2s[kk * 10 + c0];
            a0 = fmaf(hv, wrow[0], a0);
            a1 = fmaf(hv, wrow[1], a1);
            a2 = fmaf(hv, wrow[2], a2);
            a3 = fmaf(hv, wrow[3], a3);
            a4 = fmaf(hv, wrow[4], a4);
        }
        float* o = out + (size_t)(row0 + r) * 10 + c0;
        o[0] = a0; o[1] = a1; o[2] = a2; o[3] = a3; o[4] = a4;
    }
}

// ---------------------------------------------------------------------------
extern "C" void kernel_launch(void* const* d_in, const int* in_sizes, int n_in,
                              void* d_out, int out_size, void* d_ws, size_t ws_size,
                              hipStream_t stream) {
    const float* feats = (const float*)d_in[0];
    const float* Wq    = (const float*)d_in[1];
    const float* Wk    = (const float*)d_in[2];
    const float* Wv    = (const float*)d_in[3];
    const float* Wo    = (const float*)d_in[4];
    const float* W1    = (const float*)d_in[5];
    const float* b1    = (const float*)d_in[6];
    const float* W2    = (const float*)d_in[7];
    const float* b2    = (const float*)d_in[8];
    const int*   adj   = (const int*)d_in[9];
    float* out = (float*)d_out;

    float* ws = (float*)d_ws;
    const size_t ED = (size_t)E_EDGES * DIM;   // 4,194,304 elements
    float* qbuf = ws;                                    // f32 q
    __hip_bfloat16* kbuf = (__hip_bfloat16*)(ws + ED);   // bf16 k, pair-major
    __hip_bfloat16* vbuf = kbuf + ED;                    // bf16 v, pair-major
    __hip_bfloat16* ctxb = vbuf + ED;                    // bf16 ctx [E][128]
    __hip_bfloat16* wt   = ctxb + ED;                    // 3*16384 bf16
    __hip_bfloat16* wft  = wt + 3 * 16384;               // 16384 bf16

    k_prep<<<67, 256, 0, stream>>>(Wq, Wk, Wv, Wo, W1, wt, wft);
    k_qkv<<<E_EDGES / 128, 256, 0, stream>>>(feats, wt, qbuf, kbuf, vbuf);
    k_attn_pass<<<E_EDGES / 4, 256, 0, stream>>>(qbuf, kbuf, vbuf, adj, ctxb, 0);
    k_attn_pass<<<E_EDGES / 4, 256, 0, stream>>>(qbuf, kbuf, vbuf, adj, ctxb, 1);
    k_mlp<<<E_EDGES / 128, 256, 0, stream>>>(ctxb, wft, b1, W2, b2, out);
}